// Round 6
// baseline (253.958 us; speedup 1.0000x reference)
//
#include <hip/hip_runtime.h>
#include <hip/hip_fp16.h>

#define N_NODES 65536
#define N_EDGES 1048576
#define F 128
#define NBUCK 256          // dst >> 8

typedef unsigned long long ull;
typedef _Float16 half8 __attribute__((ext_vector_type(8)));
typedef float floatx4 __attribute__((ext_vector_type(4)));

// ---------------- bucket partition ----------------

__global__ __launch_bounds__(256) void k_zero256(int* gcnt) {
    gcnt[threadIdx.x] = 0;
}

__global__ __launch_bounds__(256) void k_bcount(const int* __restrict__ dst,
                                                int* __restrict__ gcnt) {
    __shared__ int hist[NBUCK];
    int t = threadIdx.x;
    hist[t] = 0;
    __syncthreads();
    int base = blockIdx.x * 4096;
#pragma unroll
    for (int i = 0; i < 16; ++i) {
        int d = dst[base + i * 256 + t];
        atomicAdd(&hist[d >> 8], 1);
    }
    __syncthreads();
    atomicAdd(&gcnt[t], hist[t]);
}

__global__ __launch_bounds__(256) void k_bscan(const int* __restrict__ gcnt,
                                               int* __restrict__ boff,
                                               int* __restrict__ gfill) {
    __shared__ int s[256];
    int t = threadIdx.x;
    int v = gcnt[t];
    s[t] = v;
    __syncthreads();
    for (int off = 1; off < 256; off <<= 1) {
        int tv = (t >= off) ? s[t - off] : 0;
        __syncthreads();
        s[t] += tv;
        __syncthreads();
    }
    int excl = s[t] - v;
    boff[t] = excl;
    gfill[t] = excl;
    if (t == 255) boff[256] = N_EDGES;
}

// brec: ew(32) | dloc(8 @ bit16) | src(16)
__global__ __launch_bounds__(256) void k_bpart(const int* __restrict__ srcArr,
                                               const int* __restrict__ dstArr,
                                               const float* __restrict__ ew,
                                               int* __restrict__ gfill,
                                               ull* __restrict__ brec) {
    __shared__ int hist[NBUCK];
    __shared__ int cur[NBUCK];
    int t = threadIdx.x;
    hist[t] = 0;
    __syncthreads();
    int base = blockIdx.x * 4096;
    int dv[16];
#pragma unroll
    for (int i = 0; i < 16; ++i) {
        dv[i] = dstArr[base + i * 256 + t];
        atomicAdd(&hist[dv[i] >> 8], 1);
    }
    __syncthreads();
    cur[t] = atomicAdd(&gfill[t], hist[t]);
    __syncthreads();
#pragma unroll
    for (int i = 0; i < 16; ++i) {
        int e = base + i * 256 + t;
        int d = dv[i];
        unsigned int s = (unsigned int)srcArr[e];
        unsigned int wb = __float_as_uint(ew[e]);
        int pos = atomicAdd(&cur[d >> 8], 1);
        brec[pos] = ((ull)wb << 32) | ((ull)(d & 255) << 16) | (ull)s;
    }
}

// per-bucket CSR build; edges within each node ordered by coarse src range
// (src>>13, 8 ranges) so the aggregate's gathers sweep src-space coherently.
__global__ __launch_bounds__(256) void k_build(const ull* __restrict__ brec,
                                               const int* __restrict__ boff,
                                               float* __restrict__ dinv,
                                               int* __restrict__ row_ptr,
                                               ull* __restrict__ edge8) {
    __shared__ ull packed[256];
    __shared__ int h2[256 * 8];   // (dloc, src-range) counts -> cursors
    __shared__ int sc[256];
    int t = threadIdx.x;
    int b = blockIdx.x;
    packed[t] = 0ULL;
#pragma unroll
    for (int i = 0; i < 8; ++i) h2[t * 8 + i] = 0;
    __syncthreads();

    int beg = boff[b], end = boff[b + 1];
    for (int j = beg + t; j < end; j += 256) {
        ull r = brec[j];
        int dloc = (int)((r >> 16) & 255);
        int src = (int)(r & 0xFFFF);
        float w = __uint_as_float((unsigned int)(r >> 32));
        ull fx = (ull)(w * 1073741824.0f);  // 2^30 fixed point
        atomicAdd(&packed[dloc], (1ULL << 40) | fx);
        atomicAdd(&h2[dloc * 8 + (src >> 13)], 1);
    }
    __syncthreads();

    ull p = packed[t];
    int c = (int)(p >> 40);
    float deg = 1.0f + (float)(p & ((1ULL << 40) - 1)) * (1.0f / 1073741824.0f);
    dinv[b * 256 + t] = rsqrtf(deg);

    sc[t] = c;
    __syncthreads();
    for (int off = 1; off < 256; off <<= 1) {
        int tv = (t >= off) ? sc[t - off] : 0;
        __syncthreads();
        sc[t] += tv;
        __syncthreads();
    }
    int excl = sc[t] - c;
    row_ptr[b * 256 + t] = beg + excl;
    if (b == NBUCK - 1 && t == 255) row_ptr[N_NODES] = N_EDGES;

    // convert per-(node,range) counts to cursors
    int base = beg + excl;
    int cum = 0;
#pragma unroll
    for (int r8 = 0; r8 < 8; ++r8) {
        int cc = h2[t * 8 + r8];
        h2[t * 8 + r8] = base + cum;
        cum += cc;
    }
    __syncthreads();

    for (int j = beg + t; j < end; j += 256) {
        ull r = brec[j];
        int dloc = (int)((r >> 16) & 255);
        int src = (int)(r & 0xFFFF);
        int pos = atomicAdd(&h2[dloc * 8 + (src >> 13)], 1);
        edge8[pos] = (r & 0xFFFFFFFF00000000ULL) | (ull)src;  // ew | src
    }
}

// coef' = dinv[src] * ew   (dinv[dst] folded into aggregate epilogue)
__global__ __launch_bounds__(256) void k_coef(ull* __restrict__ edge8,
                                              const float* __restrict__ dinv) {
    int e0 = (blockIdx.x * 256 + threadIdx.x) * 4;
#pragma unroll
    for (int i = 0; i < 4; ++i) {
        int e = e0 + i;
        ull r = edge8[e];
        int s = (int)(r & 0xFFFF);
        float w = __uint_as_float((unsigned int)(r >> 32));
        float c = dinv[s] * w;
        edge8[e] = ((ull)__float_as_uint(c) << 32) | (r & 0xFFFFULL);
    }
}

// ---------------- MFMA GEMM: Y[Nx128] (fp16) = X[Nx128] (fp32) @ W[128x128] ----
// fp32 emulated via fp16 hi/lo split of BOTH operands, 3 products into fp32 acc
// (hi*hi + hi*lo + lo*hi; lo*lo ~2^-22, dropped). Numerically ~fp32.

__global__ __launch_bounds__(256) void k_gemm_mfma(const float* __restrict__ X,
                                                   const float* __restrict__ W,
                                                   __half* __restrict__ Y) {
    __shared__ _Float16 Ah[128][40];   // X tile hi, [row][k], pad->2-way-free
    __shared__ _Float16 Al[128][40];
    __shared__ _Float16 Bh[128][40];   // W tile transposed: Bh[n][k] = hi(W[k][n])
    __shared__ _Float16 Bl[128][40];

    const int tid = threadIdx.x;
    const int wv = tid >> 6;
    const int ln = tid & 63;
    const long rowbase = (long)blockIdx.x * 128;

    floatx4 acc[2][8];
#pragma unroll
    for (int i = 0; i < 2; ++i)
#pragma unroll
        for (int j = 0; j < 8; ++j) acc[i][j] = (floatx4)(0.f);

    for (int k0 = 0; k0 < 128; k0 += 32) {
        // stage X: thread -> (row, 16-wide k half)
        {
            int row = tid >> 1;
            int kh = (tid & 1) * 16;
            const float* src = &X[(rowbase + row) * 128 + k0 + kh];
            _Float16 hi[16], lo[16];
#pragma unroll
            for (int i = 0; i < 16; i += 4) {
                float4 v = *(const float4*)&src[i];
                hi[i + 0] = (_Float16)v.x; lo[i + 0] = (_Float16)(v.x - (float)hi[i + 0]);
                hi[i + 1] = (_Float16)v.y; lo[i + 1] = (_Float16)(v.y - (float)hi[i + 1]);
                hi[i + 2] = (_Float16)v.z; lo[i + 2] = (_Float16)(v.z - (float)hi[i + 2]);
                hi[i + 3] = (_Float16)v.w; lo[i + 3] = (_Float16)(v.w - (float)hi[i + 3]);
            }
            *(half8*)&Ah[row][kh] = *(half8*)&hi[0];
            *(half8*)&Ah[row][kh + 8] = *(half8*)&hi[8];
            *(half8*)&Al[row][kh] = *(half8*)&lo[0];
            *(half8*)&Al[row][kh + 8] = *(half8*)&lo[8];
        }
        // stage W transposed: thread -> (col n, 16-wide k half)
        {
            int n = tid & 127;
            int kh = (tid >> 7) * 16;
            _Float16 hi[16], lo[16];
#pragma unroll
            for (int i = 0; i < 16; ++i) {
                float v = W[(k0 + kh + i) * 128 + n];
                hi[i] = (_Float16)v;
                lo[i] = (_Float16)(v - (float)hi[i]);
            }
            *(half8*)&Bh[n][kh] = *(half8*)&hi[0];
            *(half8*)&Bh[n][kh + 8] = *(half8*)&hi[8];
            *(half8*)&Bl[n][kh] = *(half8*)&lo[0];
            *(half8*)&Bl[n][kh + 8] = *(half8*)&lo[8];
        }
        __syncthreads();

        // one 16x16x32 k-step covers the whole BK=32 tile
        int arow0 = wv * 32 + (ln & 15);
        int kq = (ln >> 4) * 8;
        half8 a_hi0 = *(const half8*)&Ah[arow0][kq];
        half8 a_hi1 = *(const half8*)&Ah[arow0 + 16][kq];
        half8 a_lo0 = *(const half8*)&Al[arow0][kq];
        half8 a_lo1 = *(const half8*)&Al[arow0 + 16][kq];
#pragma unroll
        for (int ct = 0; ct < 8; ++ct) {
            int bcol = ct * 16 + (ln & 15);
            half8 b_hi = *(const half8*)&Bh[bcol][kq];
            half8 b_lo = *(const half8*)&Bl[bcol][kq];
            acc[0][ct] = __builtin_amdgcn_mfma_f32_16x16x32_f16(a_hi0, b_hi, acc[0][ct], 0, 0, 0);
            acc[0][ct] = __builtin_amdgcn_mfma_f32_16x16x32_f16(a_hi0, b_lo, acc[0][ct], 0, 0, 0);
            acc[0][ct] = __builtin_amdgcn_mfma_f32_16x16x32_f16(a_lo0, b_hi, acc[0][ct], 0, 0, 0);
            acc[1][ct] = __builtin_amdgcn_mfma_f32_16x16x32_f16(a_hi1, b_hi, acc[1][ct], 0, 0, 0);
            acc[1][ct] = __builtin_amdgcn_mfma_f32_16x16x32_f16(a_hi1, b_lo, acc[1][ct], 0, 0, 0);
            acc[1][ct] = __builtin_amdgcn_mfma_f32_16x16x32_f16(a_lo1, b_hi, acc[1][ct], 0, 0, 0);
        }
        __syncthreads();
    }

    // epilogue: C/D layout col = lane&15, row = (lane>>4)*4 + reg
#pragma unroll
    for (int rt = 0; rt < 2; ++rt)
#pragma unroll
        for (int ct = 0; ct < 8; ++ct)
#pragma unroll
            for (int reg = 0; reg < 4; ++reg) {
                long row = rowbase + wv * 32 + rt * 16 + (ln >> 4) * 4 + reg;
                Y[row * 128 + ct * 16 + (ln & 15)] = __float2half(acc[rt][ct][reg]);
            }
}

// ---------------- fp32 GEMM (kept for FC) ----------------

template <int BN, bool BIAS>
__global__ __launch_bounds__(256) void k_gemm(const float* __restrict__ X,
                                              const float* __restrict__ W,
                                              const float* __restrict__ bias,
                                              float* __restrict__ C) {
    constexpr int TN = BN / 16;
    __shared__ float Xs[32][132];
    __shared__ float Ws[32][BN + 4];

    const int tid = threadIdx.x;
    const int tr = tid >> 4;
    const int tc = tid & 15;
    const long rowbase = (long)blockIdx.x * 128;

    float acc[8][TN];
#pragma unroll
    for (int i = 0; i < 8; ++i)
#pragma unroll
        for (int j = 0; j < TN; ++j) acc[i][j] = 0.f;

    for (int kk = 0; kk < 128; kk += 32) {
#pragma unroll
        for (int t = 0; t < 4; ++t) {
            int q = tid + t * 256;
            int row = q >> 3;
            int c4 = q & 7;
            float4 v = *(const float4*)&X[(rowbase + row) * 128 + kk + c4 * 4];
            Xs[c4 * 4 + 0][row] = v.x;
            Xs[c4 * 4 + 1][row] = v.y;
            Xs[c4 * 4 + 2][row] = v.z;
            Xs[c4 * 4 + 3][row] = v.w;
        }
#pragma unroll
        for (int t = 0; t < (32 * BN / 4) / 256; ++t) {
            int q = tid + t * 256;
            int row = q / (BN / 4);
            int c4 = q % (BN / 4);
            *(float4*)&Ws[row][c4 * 4] = *(const float4*)&W[(kk + row) * BN + c4 * 4];
        }
        __syncthreads();

#pragma unroll 8
        for (int k = 0; k < 32; ++k) {
            float a[8], b[TN];
            *(float4*)&a[0] = *(const float4*)&Xs[k][tr * 8];
            *(float4*)&a[4] = *(const float4*)&Xs[k][tr * 8 + 4];
#pragma unroll
            for (int j = 0; j < TN; j += 4)
                *(float4*)&b[j] = *(const float4*)&Ws[k][tc * TN + j];
#pragma unroll
            for (int i = 0; i < 8; ++i)
#pragma unroll
                for (int j = 0; j < TN; ++j)
                    acc[i][j] = fmaf(a[i], b[j], acc[i][j]);
        }
        __syncthreads();
    }

#pragma unroll
    for (int i = 0; i < 8; ++i) {
        long row = rowbase + tr * 8 + i;
#pragma unroll
        for (int j = 0; j < TN; j += 4) {
            float4 v;
            v.x = acc[i][j];
            v.y = acc[i][j + 1];
            v.z = acc[i][j + 2];
            v.w = acc[i][j + 3];
            if (BIAS) {
                v.x += bias[tc * TN + j];
                v.y += bias[tc * TN + j + 1];
                v.z += bias[tc * TN + j + 2];
                v.w += bias[tc * TN + j + 3];
            }
            *(float4*)&C[row * BN + tc * TN + j] = v;
        }
    }
}

// ---------------- CSR gather aggregation (fp16 h, feature-split halves) --------
// grid = 2 * N/4 blocks; first 16384 blocks do features 0..63, rest 64..127.
// One wave per (node, feature-half); lane covers one feature (2B gathers,
// 128B/row per edge -> 8MB instantaneous working set -> better L2 hit).

__global__ __launch_bounds__(256) void k_aggregate(const __half* __restrict__ hlin,
                                                   const int* __restrict__ row_ptr,
                                                   const ull* __restrict__ edge8,
                                                   const float* __restrict__ dinv,
                                                   const float* __restrict__ bias,
                                                   float* __restrict__ out,
                                                   int do_relu) {
    int wave = threadIdx.x >> 6;
    int lane = threadIdx.x & 63;
    int hf = blockIdx.x >> 14;
    int n = ((blockIdx.x & 16383) << 2) + wave;
    int f = (hf << 6) + lane;

    float di = dinv[n];
    float scl = di * di;

    float h0 = __half2float(hlin[(size_t)n * 128 + f]);
    float a0 = 0.f, a1 = 0.f, a2 = 0.f, a3 = 0.f, a4 = 0.f, a5 = 0.f, a6 = 0.f, a7 = 0.f;

    int beg = row_ptr[n];
    int end = row_ptr[n + 1];
    for (int jb = beg; jb < end; jb += 64) {
        int nload = end - jb;
        if (nload > 64) nload = 64;
        ull r = 0ULL;
        if (lane < nload) r = edge8[jb + lane];
        for (int q = 0; q < nload; q += 8) {
            ull r0 = __shfl(r, q + 0), r1 = __shfl(r, q + 1);
            ull r2 = __shfl(r, q + 2), r3 = __shfl(r, q + 3);
            ull r4 = __shfl(r, q + 4), r5 = __shfl(r, q + 5);
            ull r6 = __shfl(r, q + 6), r7 = __shfl(r, q + 7);
            float g0 = __half2float(hlin[(size_t)(r0 & 0xFFFF) * 128 + f]);
            float g1 = __half2float(hlin[(size_t)(r1 & 0xFFFF) * 128 + f]);
            float g2 = __half2float(hlin[(size_t)(r2 & 0xFFFF) * 128 + f]);
            float g3 = __half2float(hlin[(size_t)(r3 & 0xFFFF) * 128 + f]);
            float g4 = __half2float(hlin[(size_t)(r4 & 0xFFFF) * 128 + f]);
            float g5 = __half2float(hlin[(size_t)(r5 & 0xFFFF) * 128 + f]);
            float g6 = __half2float(hlin[(size_t)(r6 & 0xFFFF) * 128 + f]);
            float g7 = __half2float(hlin[(size_t)(r7 & 0xFFFF) * 128 + f]);
            a0 = fmaf(__uint_as_float((unsigned int)(r0 >> 32)), g0, a0);
            a1 = fmaf(__uint_as_float((unsigned int)(r1 >> 32)), g1, a1);
            a2 = fmaf(__uint_as_float((unsigned int)(r2 >> 32)), g2, a2);
            a3 = fmaf(__uint_as_float((unsigned int)(r3 >> 32)), g3, a3);
            a4 = fmaf(__uint_as_float((unsigned int)(r4 >> 32)), g4, a4);
            a5 = fmaf(__uint_as_float((unsigned int)(r5 >> 32)), g5, a5);
            a6 = fmaf(__uint_as_float((unsigned int)(r6 >> 32)), g6, a6);
            a7 = fmaf(__uint_as_float((unsigned int)(r7 >> 32)), g7, a7);
        }
    }

    float sum = ((a0 + a1) + (a2 + a3)) + ((a4 + a5) + (a6 + a7));
    float acc = fmaf(di, sum, fmaf(scl, h0, bias[f]));
    if (do_relu) acc = fmaxf(acc, 0.f);
    out[(size_t)n * 128 + f] = acc;
}

// ---------------- launch ----------------

extern "C" void kernel_launch(void* const* d_in, const int* in_sizes, int n_in,
                              void* d_out, int out_size, void* d_ws, size_t ws_size,
                              hipStream_t stream) {
    const float* x   = (const float*)d_in[0];
    const int*   ei  = (const int*)d_in[1];
    const float* ew  = (const float*)d_in[2];
    const float* W1  = (const float*)d_in[4];
    const float* b1  = (const float*)d_in[5];
    const float* W2  = (const float*)d_in[6];
    const float* b2  = (const float*)d_in[7];
    const float* fcW = (const float*)d_in[8];
    const float* fcb = (const float*)d_in[9];
    float* out = (float*)d_out;

    const int* srcArr = ei;
    const int* dstArr = ei + N_EDGES;

    char* w = (char*)d_ws;
    int* gcnt = (int*)w;               w += 256 * 4;
    int* boff = (int*)w;               w += 257 * 4;
    int* gfill = (int*)w;              w += 256 * 4;
    w += 4;
    float* dinv = (float*)w;           w += (size_t)N_NODES * 4;
    int* row_ptr = (int*)w;            w += (size_t)(N_NODES + 64) * 4;
    ull* edge8 = (ull*)w;              w += (size_t)N_EDGES * 8;
    __half* bufH = (__half*)w;         w += (size_t)N_NODES * F * 2;  // 16MB
    float* bufB = (float*)w;           w += (size_t)N_NODES * F * 4;  // 32MB
    ull* brec = (ull*)bufH;            // 8MB, dead before gemm1 writes bufH

    k_zero256<<<1, 256, 0, stream>>>(gcnt);
    k_bcount<<<N_EDGES / 4096, 256, 0, stream>>>(dstArr, gcnt);
    k_bscan<<<1, 256, 0, stream>>>(gcnt, boff, gfill);
    k_bpart<<<N_EDGES / 4096, 256, 0, stream>>>(srcArr, dstArr, ew, gfill, brec);
    k_build<<<NBUCK, 256, 0, stream>>>(brec, boff, dinv, row_ptr, edge8);
    k_coef<<<N_EDGES / 1024, 256, 0, stream>>>(edge8, dinv);

    // layer 1
    k_gemm_mfma<<<512, 256, 0, stream>>>(x, W1, bufH);
    k_aggregate<<<2 * (N_NODES / 4), 256, 0, stream>>>(bufH, row_ptr, edge8, dinv, b1,
                                                       bufB, 1);
    // layer 2
    k_gemm_mfma<<<512, 256, 0, stream>>>(bufB, W2, bufH);
    k_aggregate<<<2 * (N_NODES / 4), 256, 0, stream>>>(bufH, row_ptr, edge8, dinv, b2,
                                                       bufB, 1);
    // FC (fp32)
    k_gemm<64, true><<<512, 256, 0, stream>>>(bufB, fcW, fcb, out);
}

// Round 7
// 202.299 us; speedup vs baseline: 1.2554x; 1.2554x over previous
//
#include <hip/hip_runtime.h>
#include <hip/hip_fp16.h>

#define N_NODES 65536
#define N_EDGES 1048576
#define F 128
#define NBUCK 256          // dst >> 8

typedef unsigned long long ull;
typedef _Float16 half8 __attribute__((ext_vector_type(8)));
typedef float floatx4 __attribute__((ext_vector_type(4)));

// ---------------- bucket partition ----------------

__global__ __launch_bounds__(256) void k_zero256(int* gcnt) {
    gcnt[threadIdx.x] = 0;
}

__global__ __launch_bounds__(256) void k_bcount(const int* __restrict__ dst,
                                                int* __restrict__ gcnt) {
    __shared__ int hist[NBUCK];
    int t = threadIdx.x;
    hist[t] = 0;
    __syncthreads();
    int base = blockIdx.x * 4096;
#pragma unroll
    for (int i = 0; i < 16; ++i) {
        int d = dst[base + i * 256 + t];
        atomicAdd(&hist[d >> 8], 1);
    }
    __syncthreads();
    atomicAdd(&gcnt[t], hist[t]);
}

__global__ __launch_bounds__(256) void k_bscan(const int* __restrict__ gcnt,
                                               int* __restrict__ boff,
                                               int* __restrict__ gfill) {
    __shared__ int s[256];
    int t = threadIdx.x;
    int v = gcnt[t];
    s[t] = v;
    __syncthreads();
    for (int off = 1; off < 256; off <<= 1) {
        int tv = (t >= off) ? s[t - off] : 0;
        __syncthreads();
        s[t] += tv;
        __syncthreads();
    }
    int excl = s[t] - v;
    boff[t] = excl;
    gfill[t] = excl;
    if (t == 255) boff[256] = N_EDGES;
}

// brec: ew(32) | dloc(8 @ bit16) | src(16)
__global__ __launch_bounds__(256) void k_bpart(const int* __restrict__ srcArr,
                                               const int* __restrict__ dstArr,
                                               const float* __restrict__ ew,
                                               int* __restrict__ gfill,
                                               ull* __restrict__ brec) {
    __shared__ int hist[NBUCK];
    __shared__ int cur[NBUCK];
    int t = threadIdx.x;
    hist[t] = 0;
    __syncthreads();
    int base = blockIdx.x * 4096;
    int dv[16];
#pragma unroll
    for (int i = 0; i < 16; ++i) {
        dv[i] = dstArr[base + i * 256 + t];
        atomicAdd(&hist[dv[i] >> 8], 1);
    }
    __syncthreads();
    cur[t] = atomicAdd(&gfill[t], hist[t]);
    __syncthreads();
#pragma unroll
    for (int i = 0; i < 16; ++i) {
        int e = base + i * 256 + t;
        int d = dv[i];
        unsigned int s = (unsigned int)srcArr[e];
        unsigned int wb = __float_as_uint(ew[e]);
        int pos = atomicAdd(&cur[d >> 8], 1);
        brec[pos] = ((ull)wb << 32) | ((ull)(d & 255) << 16) | (ull)s;
    }
}

// per-bucket CSR build; edges within each node ordered by coarse src range
// (src>>13) so the aggregate's 8-wide gather batches sweep src-space coherently.
__global__ __launch_bounds__(256) void k_build(const ull* __restrict__ brec,
                                               const int* __restrict__ boff,
                                               float* __restrict__ dinv,
                                               int* __restrict__ row_ptr,
                                               ull* __restrict__ edge8) {
    __shared__ ull packed[256];
    __shared__ int h2[256 * 8];
    __shared__ int sc[256];
    int t = threadIdx.x;
    int b = blockIdx.x;
    packed[t] = 0ULL;
#pragma unroll
    for (int i = 0; i < 8; ++i) h2[t * 8 + i] = 0;
    __syncthreads();

    int beg = boff[b], end = boff[b + 1];
    for (int j = beg + t; j < end; j += 256) {
        ull r = brec[j];
        int dloc = (int)((r >> 16) & 255);
        int src = (int)(r & 0xFFFF);
        float w = __uint_as_float((unsigned int)(r >> 32));
        ull fx = (ull)(w * 1073741824.0f);  // 2^30 fixed point
        atomicAdd(&packed[dloc], (1ULL << 40) | fx);
        atomicAdd(&h2[dloc * 8 + (src >> 13)], 1);
    }
    __syncthreads();

    ull p = packed[t];
    int c = (int)(p >> 40);
    float deg = 1.0f + (float)(p & ((1ULL << 40) - 1)) * (1.0f / 1073741824.0f);
    dinv[b * 256 + t] = rsqrtf(deg);

    sc[t] = c;
    __syncthreads();
    for (int off = 1; off < 256; off <<= 1) {
        int tv = (t >= off) ? sc[t - off] : 0;
        __syncthreads();
        sc[t] += tv;
        __syncthreads();
    }
    int excl = sc[t] - c;
    row_ptr[b * 256 + t] = beg + excl;
    if (b == NBUCK - 1 && t == 255) row_ptr[N_NODES] = N_EDGES;

    int base = beg + excl;
    int cum = 0;
#pragma unroll
    for (int r8 = 0; r8 < 8; ++r8) {
        int cc = h2[t * 8 + r8];
        h2[t * 8 + r8] = base + cum;
        cum += cc;
    }
    __syncthreads();

    for (int j = beg + t; j < end; j += 256) {
        ull r = brec[j];
        int dloc = (int)((r >> 16) & 255);
        int src = (int)(r & 0xFFFF);
        int pos = atomicAdd(&h2[dloc * 8 + (src >> 13)], 1);
        edge8[pos] = (r & 0xFFFFFFFF00000000ULL) | (ull)src;  // ew | src
    }
}

// coef' = dinv[src] * ew   (dinv[dst] folded into aggregate epilogue)
__global__ __launch_bounds__(256) void k_coef(ull* __restrict__ edge8,
                                              const float* __restrict__ dinv) {
    int e0 = (blockIdx.x * 256 + threadIdx.x) * 4;
#pragma unroll
    for (int i = 0; i < 4; ++i) {
        int e = e0 + i;
        ull r = edge8[e];
        int s = (int)(r & 0xFFFF);
        float w = __uint_as_float((unsigned int)(r >> 32));
        float c = dinv[s] * w;
        edge8[e] = ((ull)__float_as_uint(c) << 32) | (r & 0xFFFFULL);
    }
}

// ---------------- MFMA GEMM: Y[Nx128] (fp16) = X[Nx128] (fp32) @ W[128x128] ----
// fp32 emulated via fp16 hi/lo split of BOTH operands, 3 products into fp32 acc.

__global__ __launch_bounds__(256) void k_gemm_mfma(const float* __restrict__ X,
                                                   const float* __restrict__ W,
                                                   __half* __restrict__ Y) {
    __shared__ _Float16 Ah[128][40];
    __shared__ _Float16 Al[128][40];
    __shared__ _Float16 Bh[128][40];
    __shared__ _Float16 Bl[128][40];

    const int tid = threadIdx.x;
    const int wv = tid >> 6;
    const int ln = tid & 63;
    const long rowbase = (long)blockIdx.x * 128;

    floatx4 acc[2][8];
#pragma unroll
    for (int i = 0; i < 2; ++i)
#pragma unroll
        for (int j = 0; j < 8; ++j) acc[i][j] = (floatx4)(0.f);

    for (int k0 = 0; k0 < 128; k0 += 32) {
        {
            int row = tid >> 1;
            int kh = (tid & 1) * 16;
            const float* src = &X[(rowbase + row) * 128 + k0 + kh];
            _Float16 hi[16], lo[16];
#pragma unroll
            for (int i = 0; i < 16; i += 4) {
                float4 v = *(const float4*)&src[i];
                hi[i + 0] = (_Float16)v.x; lo[i + 0] = (_Float16)(v.x - (float)hi[i + 0]);
                hi[i + 1] = (_Float16)v.y; lo[i + 1] = (_Float16)(v.y - (float)hi[i + 1]);
                hi[i + 2] = (_Float16)v.z; lo[i + 2] = (_Float16)(v.z - (float)hi[i + 2]);
                hi[i + 3] = (_Float16)v.w; lo[i + 3] = (_Float16)(v.w - (float)hi[i + 3]);
            }
            *(half8*)&Ah[row][kh] = *(half8*)&hi[0];
            *(half8*)&Ah[row][kh + 8] = *(half8*)&hi[8];
            *(half8*)&Al[row][kh] = *(half8*)&lo[0];
            *(half8*)&Al[row][kh + 8] = *(half8*)&lo[8];
        }
        {
            int n = tid & 127;
            int kh = (tid >> 7) * 16;
            _Float16 hi[16], lo[16];
#pragma unroll
            for (int i = 0; i < 16; ++i) {
                float v = W[(k0 + kh + i) * 128 + n];
                hi[i] = (_Float16)v;
                lo[i] = (_Float16)(v - (float)hi[i]);
            }
            *(half8*)&Bh[n][kh] = *(half8*)&hi[0];
            *(half8*)&Bh[n][kh + 8] = *(half8*)&hi[8];
            *(half8*)&Bl[n][kh] = *(half8*)&lo[0];
            *(half8*)&Bl[n][kh + 8] = *(half8*)&lo[8];
        }
        __syncthreads();

        int arow0 = wv * 32 + (ln & 15);
        int kq = (ln >> 4) * 8;
        half8 a_hi0 = *(const half8*)&Ah[arow0][kq];
        half8 a_hi1 = *(const half8*)&Ah[arow0 + 16][kq];
        half8 a_lo0 = *(const half8*)&Al[arow0][kq];
        half8 a_lo1 = *(const half8*)&Al[arow0 + 16][kq];
#pragma unroll
        for (int ct = 0; ct < 8; ++ct) {
            int bcol = ct * 16 + (ln & 15);
            half8 b_hi = *(const half8*)&Bh[bcol][kq];
            half8 b_lo = *(const half8*)&Bl[bcol][kq];
            acc[0][ct] = __builtin_amdgcn_mfma_f32_16x16x32_f16(a_hi0, b_hi, acc[0][ct], 0, 0, 0);
            acc[0][ct] = __builtin_amdgcn_mfma_f32_16x16x32_f16(a_hi0, b_lo, acc[0][ct], 0, 0, 0);
            acc[0][ct] = __builtin_amdgcn_mfma_f32_16x16x32_f16(a_lo0, b_hi, acc[0][ct], 0, 0, 0);
            acc[1][ct] = __builtin_amdgcn_mfma_f32_16x16x32_f16(a_hi1, b_hi, acc[1][ct], 0, 0, 0);
            acc[1][ct] = __builtin_amdgcn_mfma_f32_16x16x32_f16(a_hi1, b_lo, acc[1][ct], 0, 0, 0);
            acc[1][ct] = __builtin_amdgcn_mfma_f32_16x16x32_f16(a_lo1, b_hi, acc[1][ct], 0, 0, 0);
        }
        __syncthreads();
    }

#pragma unroll
    for (int rt = 0; rt < 2; ++rt)
#pragma unroll
        for (int ct = 0; ct < 8; ++ct)
#pragma unroll
            for (int reg = 0; reg < 4; ++reg) {
                long row = rowbase + wv * 32 + rt * 16 + (ln >> 4) * 4 + reg;
                Y[row * 128 + ct * 16 + (ln & 15)] = __float2half(acc[rt][ct][reg]);
            }
}

// ---------------- MFMA FC: out[Nx64] (fp32) = X[Nx128] (fp32) @ W[128x64] + b --

__global__ __launch_bounds__(256) void k_fc_mfma(const float* __restrict__ X,
                                                 const float* __restrict__ W,
                                                 const float* __restrict__ bias,
                                                 float* __restrict__ Y) {
    __shared__ _Float16 Ah[128][40];
    __shared__ _Float16 Al[128][40];
    __shared__ _Float16 Bh[64][40];
    __shared__ _Float16 Bl[64][40];

    const int tid = threadIdx.x;
    const int wv = tid >> 6;
    const int ln = tid & 63;
    const long rowbase = (long)blockIdx.x * 128;

    floatx4 acc[2][4];
#pragma unroll
    for (int i = 0; i < 2; ++i)
#pragma unroll
        for (int j = 0; j < 4; ++j) acc[i][j] = (floatx4)(0.f);

    for (int k0 = 0; k0 < 128; k0 += 32) {
        {
            int row = tid >> 1;
            int kh = (tid & 1) * 16;
            const float* src = &X[(rowbase + row) * 128 + k0 + kh];
            _Float16 hi[16], lo[16];
#pragma unroll
            for (int i = 0; i < 16; i += 4) {
                float4 v = *(const float4*)&src[i];
                hi[i + 0] = (_Float16)v.x; lo[i + 0] = (_Float16)(v.x - (float)hi[i + 0]);
                hi[i + 1] = (_Float16)v.y; lo[i + 1] = (_Float16)(v.y - (float)hi[i + 1]);
                hi[i + 2] = (_Float16)v.z; lo[i + 2] = (_Float16)(v.z - (float)hi[i + 2]);
                hi[i + 3] = (_Float16)v.w; lo[i + 3] = (_Float16)(v.w - (float)hi[i + 3]);
            }
            *(half8*)&Ah[row][kh] = *(half8*)&hi[0];
            *(half8*)&Ah[row][kh + 8] = *(half8*)&hi[8];
            *(half8*)&Al[row][kh] = *(half8*)&lo[0];
            *(half8*)&Al[row][kh + 8] = *(half8*)&lo[8];
        }
        {
            int n = tid & 63;
            int kh = (tid >> 6) * 8;   // 0,8,16,24
            _Float16 hi[8], lo[8];
#pragma unroll
            for (int i = 0; i < 8; ++i) {
                float v = W[(k0 + kh + i) * 64 + n];
                hi[i] = (_Float16)v;
                lo[i] = (_Float16)(v - (float)hi[i]);
            }
            *(half8*)&Bh[n][kh] = *(half8*)&hi[0];
            *(half8*)&Bl[n][kh] = *(half8*)&lo[0];
        }
        __syncthreads();

        int arow0 = wv * 32 + (ln & 15);
        int kq = (ln >> 4) * 8;
        half8 a_hi0 = *(const half8*)&Ah[arow0][kq];
        half8 a_hi1 = *(const half8*)&Ah[arow0 + 16][kq];
        half8 a_lo0 = *(const half8*)&Al[arow0][kq];
        half8 a_lo1 = *(const half8*)&Al[arow0 + 16][kq];
#pragma unroll
        for (int ct = 0; ct < 4; ++ct) {
            int bcol = ct * 16 + (ln & 15);
            half8 b_hi = *(const half8*)&Bh[bcol][kq];
            half8 b_lo = *(const half8*)&Bl[bcol][kq];
            acc[0][ct] = __builtin_amdgcn_mfma_f32_16x16x32_f16(a_hi0, b_hi, acc[0][ct], 0, 0, 0);
            acc[0][ct] = __builtin_amdgcn_mfma_f32_16x16x32_f16(a_hi0, b_lo, acc[0][ct], 0, 0, 0);
            acc[0][ct] = __builtin_amdgcn_mfma_f32_16x16x32_f16(a_lo0, b_hi, acc[0][ct], 0, 0, 0);
            acc[1][ct] = __builtin_amdgcn_mfma_f32_16x16x32_f16(a_hi1, b_hi, acc[1][ct], 0, 0, 0);
            acc[1][ct] = __builtin_amdgcn_mfma_f32_16x16x32_f16(a_hi1, b_lo, acc[1][ct], 0, 0, 0);
            acc[1][ct] = __builtin_amdgcn_mfma_f32_16x16x32_f16(a_lo1, b_hi, acc[1][ct], 0, 0, 0);
        }
        __syncthreads();
    }

#pragma unroll
    for (int rt = 0; rt < 2; ++rt)
#pragma unroll
        for (int ct = 0; ct < 4; ++ct)
#pragma unroll
            for (int reg = 0; reg < 4; ++reg) {
                long row = rowbase + wv * 32 + rt * 16 + (ln >> 4) * 4 + reg;
                int col = ct * 16 + (ln & 15);
                Y[row * 64 + col] = acc[rt][ct][reg] + bias[col];
            }
}

// ---------------- CSR gather aggregation (fp16 h, packed 8B edges) ----------------
// out[n] = relu( di*Sum_j coef'_j h[src_j] + di^2 h[n] + b )

__global__ __launch_bounds__(256) void k_aggregate(const __half2* __restrict__ hlin,
                                                   const int* __restrict__ row_ptr,
                                                   const ull* __restrict__ edge8,
                                                   const float* __restrict__ dinv,
                                                   const float* __restrict__ bias,
                                                   float* __restrict__ out,
                                                   int do_relu) {
    int wave = threadIdx.x >> 6;
    int lane = threadIdx.x & 63;
    int n = (blockIdx.x << 2) + wave;

    float di = dinv[n];
    float sc = di * di;

    float2 h0 = __half22float2(hlin[(size_t)n * 64 + lane]);
    float2 a0, a1, a2, a3, a4, a5, a6, a7;
    a0 = a1 = a2 = a3 = a4 = a5 = a6 = a7 = make_float2(0.f, 0.f);

    int beg = row_ptr[n];
    int end = row_ptr[n + 1];
    for (int jb = beg; jb < end; jb += 64) {
        int nload = end - jb;
        if (nload > 64) nload = 64;
        ull r = 0ULL;
        if (lane < nload) r = edge8[jb + lane];
        for (int q = 0; q < nload; q += 8) {
            ull r0 = __shfl(r, q + 0), r1 = __shfl(r, q + 1);
            ull r2 = __shfl(r, q + 2), r3 = __shfl(r, q + 3);
            ull r4 = __shfl(r, q + 4), r5 = __shfl(r, q + 5);
            ull r6 = __shfl(r, q + 6), r7 = __shfl(r, q + 7);
            int s0 = (int)(r0 & 0xFFFF), s1 = (int)(r1 & 0xFFFF);
            int s2 = (int)(r2 & 0xFFFF), s3 = (int)(r3 & 0xFFFF);
            int s4 = (int)(r4 & 0xFFFF), s5 = (int)(r5 & 0xFFFF);
            int s6 = (int)(r6 & 0xFFFF), s7 = (int)(r7 & 0xFFFF);
            float c0 = __uint_as_float((unsigned int)(r0 >> 32));
            float c1 = __uint_as_float((unsigned int)(r1 >> 32));
            float c2 = __uint_as_float((unsigned int)(r2 >> 32));
            float c3 = __uint_as_float((unsigned int)(r3 >> 32));
            float c4 = __uint_as_float((unsigned int)(r4 >> 32));
            float c5 = __uint_as_float((unsigned int)(r5 >> 32));
            float c6 = __uint_as_float((unsigned int)(r6 >> 32));
            float c7 = __uint_as_float((unsigned int)(r7 >> 32));
            __half2 g0 = hlin[(size_t)s0 * 64 + lane];
            __half2 g1 = hlin[(size_t)s1 * 64 + lane];
            __half2 g2 = hlin[(size_t)s2 * 64 + lane];
            __half2 g3 = hlin[(size_t)s3 * 64 + lane];
            __half2 g4 = hlin[(size_t)s4 * 64 + lane];
            __half2 g5 = hlin[(size_t)s5 * 64 + lane];
            __half2 g6 = hlin[(size_t)s6 * 64 + lane];
            __half2 g7 = hlin[(size_t)s7 * 64 + lane];
            float2 f0 = __half22float2(g0), f1 = __half22float2(g1);
            float2 f2 = __half22float2(g2), f3 = __half22float2(g3);
            float2 f4 = __half22float2(g4), f5 = __half22float2(g5);
            float2 f6 = __half22float2(g6), f7 = __half22float2(g7);
            a0.x = fmaf(c0, f0.x, a0.x); a0.y = fmaf(c0, f0.y, a0.y);
            a1.x = fmaf(c1, f1.x, a1.x); a1.y = fmaf(c1, f1.y, a1.y);
            a2.x = fmaf(c2, f2.x, a2.x); a2.y = fmaf(c2, f2.y, a2.y);
            a3.x = fmaf(c3, f3.x, a3.x); a3.y = fmaf(c3, f3.y, a3.y);
            a4.x = fmaf(c4, f4.x, a4.x); a4.y = fmaf(c4, f4.y, a4.y);
            a5.x = fmaf(c5, f5.x, a5.x); a5.y = fmaf(c5, f5.y, a5.y);
            a6.x = fmaf(c6, f6.x, a6.x); a6.y = fmaf(c6, f6.y, a6.y);
            a7.x = fmaf(c7, f7.x, a7.x); a7.y = fmaf(c7, f7.y, a7.y);
        }
    }

    float2 sum;
    sum.x = ((a0.x + a1.x) + (a2.x + a3.x)) + ((a4.x + a5.x) + (a6.x + a7.x));
    sum.y = ((a0.y + a1.y) + (a2.y + a3.y)) + ((a4.y + a5.y) + (a6.y + a7.y));

    float2 bb = ((const float2*)bias)[lane];
    float2 acc;
    acc.x = fmaf(di, sum.x, fmaf(sc, h0.x, bb.x));
    acc.y = fmaf(di, sum.y, fmaf(sc, h0.y, bb.y));
    if (do_relu) {
        acc.x = fmaxf(acc.x, 0.f);
        acc.y = fmaxf(acc.y, 0.f);
    }
    ((float2*)out)[(size_t)n * 64 + lane] = acc;
}

// ---------------- launch ----------------

extern "C" void kernel_launch(void* const* d_in, const int* in_sizes, int n_in,
                              void* d_out, int out_size, void* d_ws, size_t ws_size,
                              hipStream_t stream) {
    const float* x   = (const float*)d_in[0];
    const int*   ei  = (const int*)d_in[1];
    const float* ew  = (const float*)d_in[2];
    const float* W1  = (const float*)d_in[4];
    const float* b1  = (const float*)d_in[5];
    const float* W2  = (const float*)d_in[6];
    const float* b2  = (const float*)d_in[7];
    const float* fcW = (const float*)d_in[8];
    const float* fcb = (const float*)d_in[9];
    float* out = (float*)d_out;

    const int* srcArr = ei;
    const int* dstArr = ei + N_EDGES;

    char* w = (char*)d_ws;
    int* gcnt = (int*)w;               w += 256 * 4;
    int* boff = (int*)w;               w += 257 * 4;
    int* gfill = (int*)w;              w += 256 * 4;
    w += 4;
    float* dinv = (float*)w;           w += (size_t)N_NODES * 4;
    int* row_ptr = (int*)w;            w += (size_t)(N_NODES + 64) * 4;
    ull* edge8 = (ull*)w;              w += (size_t)N_EDGES * 8;
    __half* bufH = (__half*)w;         w += (size_t)N_NODES * F * 2;  // 16MB
    float* bufB = (float*)w;           w += (size_t)N_NODES * F * 4;  // 32MB
    ull* brec = (ull*)bufH;            // 8MB, dead before gemm1 writes bufH

    k_zero256<<<1, 256, 0, stream>>>(gcnt);
    k_bcount<<<N_EDGES / 4096, 256, 0, stream>>>(dstArr, gcnt);
    k_bscan<<<1, 256, 0, stream>>>(gcnt, boff, gfill);
    k_bpart<<<N_EDGES / 4096, 256, 0, stream>>>(srcArr, dstArr, ew, gfill, brec);
    k_build<<<NBUCK, 256, 0, stream>>>(brec, boff, dinv, row_ptr, edge8);
    k_coef<<<N_EDGES / 1024, 256, 0, stream>>>(edge8, dinv);

    // layer 1
    k_gemm_mfma<<<512, 256, 0, stream>>>(x, W1, bufH);
    k_aggregate<<<N_NODES / 4, 256, 0, stream>>>((const __half2*)bufH, row_ptr, edge8,
                                                 dinv, b1, bufB, 1);
    // layer 2
    k_gemm_mfma<<<512, 256, 0, stream>>>(bufB, W2, bufH);
    k_aggregate<<<N_NODES / 4, 256, 0, stream>>>((const __half2*)bufH, row_ptr, edge8,
                                                 dinv, b2, bufB, 1);
    // FC (MFMA, fp32 out)
    k_fc_mfma<<<512, 256, 0, stream>>>(bufB, fcW, fcb, out);
}

// Round 8
// 200.970 us; speedup vs baseline: 1.2637x; 1.0066x over previous
//
#include <hip/hip_runtime.h>
#include <hip/hip_fp16.h>

#define N_NODES 65536
#define N_EDGES 1048576
#define F 128
#define NBUCK 256          // dst >> 8

typedef unsigned long long ull;
typedef _Float16 half8 __attribute__((ext_vector_type(8)));
typedef float floatx4 __attribute__((ext_vector_type(4)));

// ---------------- bucket partition ----------------

__global__ __launch_bounds__(256) void k_zero256(int* gcnt) {
    gcnt[threadIdx.x] = 0;
}

__global__ __launch_bounds__(256) void k_bcount(const int* __restrict__ dst,
                                                int* __restrict__ gcnt) {
    __shared__ int hist[NBUCK];
    int t = threadIdx.x;
    hist[t] = 0;
    __syncthreads();
    int base = blockIdx.x * 4096;
#pragma unroll
    for (int i = 0; i < 16; ++i) {
        int d = dst[base + i * 256 + t];
        atomicAdd(&hist[d >> 8], 1);
    }
    __syncthreads();
    atomicAdd(&gcnt[t], hist[t]);
}

__global__ __launch_bounds__(256) void k_bscan(const int* __restrict__ gcnt,
                                               int* __restrict__ boff,
                                               int* __restrict__ gfill) {
    __shared__ int s[256];
    int t = threadIdx.x;
    int v = gcnt[t];
    s[t] = v;
    __syncthreads();
    for (int off = 1; off < 256; off <<= 1) {
        int tv = (t >= off) ? s[t - off] : 0;
        __syncthreads();
        s[t] += tv;
        __syncthreads();
    }
    int excl = s[t] - v;
    boff[t] = excl;
    gfill[t] = excl;
    if (t == 255) boff[256] = N_EDGES;
}

// brec: ew(32) | dloc(8 @ bit16) | src(16)
__global__ __launch_bounds__(256) void k_bpart(const int* __restrict__ srcArr,
                                               const int* __restrict__ dstArr,
                                               const float* __restrict__ ew,
                                               int* __restrict__ gfill,
                                               ull* __restrict__ brec) {
    __shared__ int hist[NBUCK];
    __shared__ int cur[NBUCK];
    int t = threadIdx.x;
    hist[t] = 0;
    __syncthreads();
    int base = blockIdx.x * 4096;
    int dv[16];
#pragma unroll
    for (int i = 0; i < 16; ++i) {
        dv[i] = dstArr[base + i * 256 + t];
        atomicAdd(&hist[dv[i] >> 8], 1);
    }
    __syncthreads();
    cur[t] = atomicAdd(&gfill[t], hist[t]);
    __syncthreads();
#pragma unroll
    for (int i = 0; i < 16; ++i) {
        int e = base + i * 256 + t;
        int d = dv[i];
        unsigned int s = (unsigned int)srcArr[e];
        unsigned int wb = __float_as_uint(ew[e]);
        int pos = atomicAdd(&cur[d >> 8], 1);
        brec[pos] = ((ull)wb << 32) | ((ull)(d & 255) << 16) | (ull)s;
    }
}

// per-bucket CSR build (LDS hist: count<<40 | fixed-point ew-sum)
__global__ __launch_bounds__(256) void k_build(const ull* __restrict__ brec,
                                               const int* __restrict__ boff,
                                               float* __restrict__ dinv,
                                               int* __restrict__ row_ptr,
                                               ull* __restrict__ edge8) {
    __shared__ ull packed[256];
    __shared__ int sc[256];
    __shared__ int cur[256];
    int t = threadIdx.x;
    int b = blockIdx.x;
    packed[t] = 0ULL;
    __syncthreads();

    int beg = boff[b], end = boff[b + 1];
    for (int j = beg + t; j < end; j += 256) {
        ull r = brec[j];
        int dloc = (int)((r >> 16) & 255);
        float w = __uint_as_float((unsigned int)(r >> 32));
        ull fx = (ull)(w * 1073741824.0f);  // 2^30 fixed point
        atomicAdd(&packed[dloc], (1ULL << 40) | fx);
    }
    __syncthreads();

    ull p = packed[t];
    int c = (int)(p >> 40);
    float deg = 1.0f + (float)(p & ((1ULL << 40) - 1)) * (1.0f / 1073741824.0f);
    dinv[b * 256 + t] = rsqrtf(deg);

    sc[t] = c;
    __syncthreads();
    for (int off = 1; off < 256; off <<= 1) {
        int tv = (t >= off) ? sc[t - off] : 0;
        __syncthreads();
        sc[t] += tv;
        __syncthreads();
    }
    int excl = sc[t] - c;
    row_ptr[b * 256 + t] = beg + excl;
    if (b == NBUCK - 1 && t == 255) row_ptr[N_NODES] = N_EDGES;
    cur[t] = beg + excl;
    __syncthreads();

    for (int j = beg + t; j < end; j += 256) {
        ull r = brec[j];
        int dloc = (int)((r >> 16) & 255);
        int pos = atomicAdd(&cur[dloc], 1);
        edge8[pos] = (r & 0xFFFFFFFF00000000ULL) | (r & 0xFFFFULL);  // ew | src
    }
}

// coef' = dinv[src] * ew   (dinv[dst] folded into aggregate epilogue)
__global__ __launch_bounds__(256) void k_coef(ull* __restrict__ edge8,
                                              const float* __restrict__ dinv) {
    int e0 = (blockIdx.x * 256 + threadIdx.x) * 4;
#pragma unroll
    for (int i = 0; i < 4; ++i) {
        int e = e0 + i;
        ull r = edge8[e];
        int s = (int)(r & 0xFFFF);
        float w = __uint_as_float((unsigned int)(r >> 32));
        float c = dinv[s] * w;
        edge8[e] = ((ull)__float_as_uint(c) << 32) | (r & 0xFFFFULL);
    }
}

// ---------------- MFMA GEMM (fp32 A via hi/lo): Y[Nx128] fp16 = X fp32 @ W ----

__global__ __launch_bounds__(256) void k_gemm_mfma(const float* __restrict__ X,
                                                   const float* __restrict__ W,
                                                   __half* __restrict__ Y) {
    __shared__ _Float16 Ah[128][40];
    __shared__ _Float16 Al[128][40];
    __shared__ _Float16 Bh[128][40];
    __shared__ _Float16 Bl[128][40];

    const int tid = threadIdx.x;
    const int wv = tid >> 6;
    const int ln = tid & 63;
    const long rowbase = (long)blockIdx.x * 128;

    floatx4 acc[2][8];
#pragma unroll
    for (int i = 0; i < 2; ++i)
#pragma unroll
        for (int j = 0; j < 8; ++j) acc[i][j] = (floatx4)(0.f);

    for (int k0 = 0; k0 < 128; k0 += 32) {
        {
            int row = tid >> 1;
            int kh = (tid & 1) * 16;
            const float* src = &X[(rowbase + row) * 128 + k0 + kh];
            _Float16 hi[16], lo[16];
#pragma unroll
            for (int i = 0; i < 16; i += 4) {
                float4 v = *(const float4*)&src[i];
                hi[i + 0] = (_Float16)v.x; lo[i + 0] = (_Float16)(v.x - (float)hi[i + 0]);
                hi[i + 1] = (_Float16)v.y; lo[i + 1] = (_Float16)(v.y - (float)hi[i + 1]);
                hi[i + 2] = (_Float16)v.z; lo[i + 2] = (_Float16)(v.z - (float)hi[i + 2]);
                hi[i + 3] = (_Float16)v.w; lo[i + 3] = (_Float16)(v.w - (float)hi[i + 3]);
            }
            *(half8*)&Ah[row][kh] = *(half8*)&hi[0];
            *(half8*)&Ah[row][kh + 8] = *(half8*)&hi[8];
            *(half8*)&Al[row][kh] = *(half8*)&lo[0];
            *(half8*)&Al[row][kh + 8] = *(half8*)&lo[8];
        }
        {
            int n = tid & 127;
            int kh = (tid >> 7) * 16;
            _Float16 hi[16], lo[16];
#pragma unroll
            for (int i = 0; i < 16; ++i) {
                float v = W[(k0 + kh + i) * 128 + n];
                hi[i] = (_Float16)v;
                lo[i] = (_Float16)(v - (float)hi[i]);
            }
            *(half8*)&Bh[n][kh] = *(half8*)&hi[0];
            *(half8*)&Bh[n][kh + 8] = *(half8*)&hi[8];
            *(half8*)&Bl[n][kh] = *(half8*)&lo[0];
            *(half8*)&Bl[n][kh + 8] = *(half8*)&lo[8];
        }
        __syncthreads();

        int arow0 = wv * 32 + (ln & 15);
        int kq = (ln >> 4) * 8;
        half8 a_hi0 = *(const half8*)&Ah[arow0][kq];
        half8 a_hi1 = *(const half8*)&Ah[arow0 + 16][kq];
        half8 a_lo0 = *(const half8*)&Al[arow0][kq];
        half8 a_lo1 = *(const half8*)&Al[arow0 + 16][kq];
#pragma unroll
        for (int ct = 0; ct < 8; ++ct) {
            int bcol = ct * 16 + (ln & 15);
            half8 b_hi = *(const half8*)&Bh[bcol][kq];
            half8 b_lo = *(const half8*)&Bl[bcol][kq];
            acc[0][ct] = __builtin_amdgcn_mfma_f32_16x16x32_f16(a_hi0, b_hi, acc[0][ct], 0, 0, 0);
            acc[0][ct] = __builtin_amdgcn_mfma_f32_16x16x32_f16(a_hi0, b_lo, acc[0][ct], 0, 0, 0);
            acc[0][ct] = __builtin_amdgcn_mfma_f32_16x16x32_f16(a_lo0, b_hi, acc[0][ct], 0, 0, 0);
            acc[1][ct] = __builtin_amdgcn_mfma_f32_16x16x32_f16(a_hi1, b_hi, acc[1][ct], 0, 0, 0);
            acc[1][ct] = __builtin_amdgcn_mfma_f32_16x16x32_f16(a_hi1, b_lo, acc[1][ct], 0, 0, 0);
            acc[1][ct] = __builtin_amdgcn_mfma_f32_16x16x32_f16(a_lo1, b_hi, acc[1][ct], 0, 0, 0);
        }
        __syncthreads();
    }

#pragma unroll
    for (int rt = 0; rt < 2; ++rt)
#pragma unroll
        for (int ct = 0; ct < 8; ++ct)
#pragma unroll
            for (int reg = 0; reg < 4; ++reg) {
                long row = rowbase + wv * 32 + rt * 16 + (ln >> 4) * 4 + reg;
                Y[row * 128 + ct * 16 + (ln & 15)] = __float2half(acc[rt][ct][reg]);
            }
}

// ---------------- MFMA GEMM (fp16 A, exact): Y[Nx128] fp16 = X fp16 @ W -------

__global__ __launch_bounds__(256) void k_gemm_mfma_h(const __half* __restrict__ X,
                                                     const float* __restrict__ W,
                                                     __half* __restrict__ Y) {
    __shared__ _Float16 Ah[128][40];
    __shared__ _Float16 Bh[128][40];
    __shared__ _Float16 Bl[128][40];

    const int tid = threadIdx.x;
    const int wv = tid >> 6;
    const int ln = tid & 63;
    const long rowbase = (long)blockIdx.x * 128;

    floatx4 acc[2][8];
#pragma unroll
    for (int i = 0; i < 2; ++i)
#pragma unroll
        for (int j = 0; j < 8; ++j) acc[i][j] = (floatx4)(0.f);

    for (int k0 = 0; k0 < 128; k0 += 32) {
        {
            int row = tid >> 1;
            int kh = (tid & 1) * 16;
            const __half* src = &X[(rowbase + row) * 128 + k0 + kh];
            *(half8*)&Ah[row][kh] = *(const half8*)&src[0];
            *(half8*)&Ah[row][kh + 8] = *(const half8*)&src[8];
        }
        {
            int n = tid & 127;
            int kh = (tid >> 7) * 16;
            _Float16 hi[16], lo[16];
#pragma unroll
            for (int i = 0; i < 16; ++i) {
                float v = W[(k0 + kh + i) * 128 + n];
                hi[i] = (_Float16)v;
                lo[i] = (_Float16)(v - (float)hi[i]);
            }
            *(half8*)&Bh[n][kh] = *(half8*)&hi[0];
            *(half8*)&Bh[n][kh + 8] = *(half8*)&hi[8];
            *(half8*)&Bl[n][kh] = *(half8*)&lo[0];
            *(half8*)&Bl[n][kh + 8] = *(half8*)&lo[8];
        }
        __syncthreads();

        int arow0 = wv * 32 + (ln & 15);
        int kq = (ln >> 4) * 8;
        half8 a0 = *(const half8*)&Ah[arow0][kq];
        half8 a1 = *(const half8*)&Ah[arow0 + 16][kq];
#pragma unroll
        for (int ct = 0; ct < 8; ++ct) {
            int bcol = ct * 16 + (ln & 15);
            half8 b_hi = *(const half8*)&Bh[bcol][kq];
            half8 b_lo = *(const half8*)&Bl[bcol][kq];
            acc[0][ct] = __builtin_amdgcn_mfma_f32_16x16x32_f16(a0, b_hi, acc[0][ct], 0, 0, 0);
            acc[0][ct] = __builtin_amdgcn_mfma_f32_16x16x32_f16(a0, b_lo, acc[0][ct], 0, 0, 0);
            acc[1][ct] = __builtin_amdgcn_mfma_f32_16x16x32_f16(a1, b_hi, acc[1][ct], 0, 0, 0);
            acc[1][ct] = __builtin_amdgcn_mfma_f32_16x16x32_f16(a1, b_lo, acc[1][ct], 0, 0, 0);
        }
        __syncthreads();
    }

#pragma unroll
    for (int rt = 0; rt < 2; ++rt)
#pragma unroll
        for (int ct = 0; ct < 8; ++ct)
#pragma unroll
            for (int reg = 0; reg < 4; ++reg) {
                long row = rowbase + wv * 32 + rt * 16 + (ln >> 4) * 4 + reg;
                Y[row * 128 + ct * 16 + (ln & 15)] = __float2half(acc[rt][ct][reg]);
            }
}

// ---------------- MFMA FC (fp16 A): out[Nx64] fp32 = X fp16 @ W[128x64] + b ----

__global__ __launch_bounds__(256) void k_fc_mfma_h(const __half* __restrict__ X,
                                                   const float* __restrict__ W,
                                                   const float* __restrict__ bias,
                                                   float* __restrict__ Y) {
    __shared__ _Float16 Ah[128][40];
    __shared__ _Float16 Bh[64][40];
    __shared__ _Float16 Bl[64][40];

    const int tid = threadIdx.x;
    const int wv = tid >> 6;
    const int ln = tid & 63;
    const long rowbase = (long)blockIdx.x * 128;

    floatx4 acc[2][4];
#pragma unroll
    for (int i = 0; i < 2; ++i)
#pragma unroll
        for (int j = 0; j < 4; ++j) acc[i][j] = (floatx4)(0.f);

    for (int k0 = 0; k0 < 128; k0 += 32) {
        {
            int row = tid >> 1;
            int kh = (tid & 1) * 16;
            const __half* src = &X[(rowbase + row) * 128 + k0 + kh];
            *(half8*)&Ah[row][kh] = *(const half8*)&src[0];
            *(half8*)&Ah[row][kh + 8] = *(const half8*)&src[8];
        }
        {
            int n = tid & 63;
            int kh = (tid >> 6) * 8;   // 0,8,16,24
            _Float16 hi[8], lo[8];
#pragma unroll
            for (int i = 0; i < 8; ++i) {
                float v = W[(k0 + kh + i) * 64 + n];
                hi[i] = (_Float16)v;
                lo[i] = (_Float16)(v - (float)hi[i]);
            }
            *(half8*)&Bh[n][kh] = *(half8*)&hi[0];
            *(half8*)&Bl[n][kh] = *(half8*)&lo[0];
        }
        __syncthreads();

        int arow0 = wv * 32 + (ln & 15);
        int kq = (ln >> 4) * 8;
        half8 a0 = *(const half8*)&Ah[arow0][kq];
        half8 a1 = *(const half8*)&Ah[arow0 + 16][kq];
#pragma unroll
        for (int ct = 0; ct < 4; ++ct) {
            int bcol = ct * 16 + (ln & 15);
            half8 b_hi = *(const half8*)&Bh[bcol][kq];
            half8 b_lo = *(const half8*)&Bl[bcol][kq];
            acc[0][ct] = __builtin_amdgcn_mfma_f32_16x16x32_f16(a0, b_hi, acc[0][ct], 0, 0, 0);
            acc[0][ct] = __builtin_amdgcn_mfma_f32_16x16x32_f16(a0, b_lo, acc[0][ct], 0, 0, 0);
            acc[1][ct] = __builtin_amdgcn_mfma_f32_16x16x32_f16(a1, b_hi, acc[1][ct], 0, 0, 0);
            acc[1][ct] = __builtin_amdgcn_mfma_f32_16x16x32_f16(a1, b_lo, acc[1][ct], 0, 0, 0);
        }
        __syncthreads();
    }

#pragma unroll
    for (int rt = 0; rt < 2; ++rt)
#pragma unroll
        for (int ct = 0; ct < 4; ++ct)
#pragma unroll
            for (int reg = 0; reg < 4; ++reg) {
                long row = rowbase + wv * 32 + rt * 16 + (ln >> 4) * 4 + reg;
                int col = ct * 16 + (ln & 15);
                Y[row * 64 + col] = acc[rt][ct][reg] + bias[col];
            }
}

// ---------------- CSR gather aggregation: 2 nodes/wave, fp16 in+out ------------
// out[n] = relu( di*Sum_j coef'_j h[src_j] + di^2 h[n] + b ), stored fp16.
// Two consecutive nodes per wave -> 16 independent gathers in flight.

__global__ __launch_bounds__(256) void k_aggregate(const __half2* __restrict__ hlin,
                                                   const int* __restrict__ row_ptr,
                                                   const ull* __restrict__ edge8,
                                                   const float* __restrict__ dinv,
                                                   const float* __restrict__ bias,
                                                   __half2* __restrict__ out) {
    int wave = threadIdx.x >> 6;
    int lane = threadIdx.x & 63;
    int nA = ((blockIdx.x << 2) + wave) * 2;
    int nB = nA + 1;

    float diA = dinv[nA], diB = dinv[nB];
    float2 hA = __half22float2(hlin[(size_t)nA * 64 + lane]);
    float2 hB = __half22float2(hlin[(size_t)nB * 64 + lane]);

    float2 aA[8], aB[8];
#pragma unroll
    for (int i = 0; i < 8; ++i) {
        aA[i] = make_float2(0.f, 0.f);
        aB[i] = make_float2(0.f, 0.f);
    }

    int begA = row_ptr[nA];
    int endA = row_ptr[nA + 1];
    int endB = row_ptr[nB + 1];
    int dA = endA - begA;
    int dB = endB - endA;
    int dmax = dA > dB ? dA : dB;

    for (int base = 0; base < dmax; base += 64) {
        int mA = dA - base; mA = mA > 64 ? 64 : mA;
        int mB = dB - base; mB = mB > 64 ? 64 : mB;
        ull rA = 0ULL, rB = 0ULL;
        if (lane < mA) rA = edge8[begA + base + lane];
        if (lane < mB) rB = edge8[endA + base + lane];
        int mmax = mA > mB ? mA : mB;
        for (int q = 0; q < mmax; q += 8) {
            if (q < mA) {
#pragma unroll
                for (int i = 0; i < 8; ++i) {
                    ull ri = __shfl(rA, q + i);
                    float ci = __uint_as_float((unsigned int)(ri >> 32));
                    float2 f = __half22float2(hlin[(size_t)(ri & 0xFFFF) * 64 + lane]);
                    aA[i].x = fmaf(ci, f.x, aA[i].x);
                    aA[i].y = fmaf(ci, f.y, aA[i].y);
                }
            }
            if (q < mB) {
#pragma unroll
                for (int i = 0; i < 8; ++i) {
                    ull ri = __shfl(rB, q + i);
                    float ci = __uint_as_float((unsigned int)(ri >> 32));
                    float2 f = __half22float2(hlin[(size_t)(ri & 0xFFFF) * 64 + lane]);
                    aB[i].x = fmaf(ci, f.x, aB[i].x);
                    aB[i].y = fmaf(ci, f.y, aB[i].y);
                }
            }
        }
    }

    float2 sA, sB;
    sA.x = ((aA[0].x + aA[1].x) + (aA[2].x + aA[3].x)) + ((aA[4].x + aA[5].x) + (aA[6].x + aA[7].x));
    sA.y = ((aA[0].y + aA[1].y) + (aA[2].y + aA[3].y)) + ((aA[4].y + aA[5].y) + (aA[6].y + aA[7].y));
    sB.x = ((aB[0].x + aB[1].x) + (aB[2].x + aB[3].x)) + ((aB[4].x + aB[5].x) + (aB[6].x + aB[7].x));
    sB.y = ((aB[0].y + aB[1].y) + (aB[2].y + aB[3].y)) + ((aB[4].y + aB[5].y) + (aB[6].y + aB[7].y));

    float2 bb = ((const float2*)bias)[lane];
    float2 oA, oB;
    oA.x = fmaxf(fmaf(diA, sA.x, fmaf(diA * diA, hA.x, bb.x)), 0.f);
    oA.y = fmaxf(fmaf(diA, sA.y, fmaf(diA * diA, hA.y, bb.y)), 0.f);
    oB.x = fmaxf(fmaf(diB, sB.x, fmaf(diB * diB, hB.x, bb.x)), 0.f);
    oB.y = fmaxf(fmaf(diB, sB.y, fmaf(diB * diB, hB.y, bb.y)), 0.f);

    out[(size_t)nA * 64 + lane] = __floats2half2_rn(oA.x, oA.y);
    out[(size_t)nB * 64 + lane] = __floats2half2_rn(oB.x, oB.y);
}

// ---------------- launch ----------------

extern "C" void kernel_launch(void* const* d_in, const int* in_sizes, int n_in,
                              void* d_out, int out_size, void* d_ws, size_t ws_size,
                              hipStream_t stream) {
    const float* x   = (const float*)d_in[0];
    const int*   ei  = (const int*)d_in[1];
    const float* ew  = (const float*)d_in[2];
    const float* W1  = (const float*)d_in[4];
    const float* b1  = (const float*)d_in[5];
    const float* W2  = (const float*)d_in[6];
    const float* b2  = (const float*)d_in[7];
    const float* fcW = (const float*)d_in[8];
    const float* fcb = (const float*)d_in[9];
    float* out = (float*)d_out;

    const int* srcArr = ei;
    const int* dstArr = ei + N_EDGES;

    char* w = (char*)d_ws;
    int* gcnt = (int*)w;               w += 256 * 4;
    int* boff = (int*)w;               w += 257 * 4;
    int* gfill = (int*)w;              w += 256 * 4;
    w += 4;
    float* dinv = (float*)w;           w += (size_t)N_NODES * 4;
    int* row_ptr = (int*)w;            w += (size_t)(N_NODES + 64) * 4;
    ull* edge8 = (ull*)w;              w += (size_t)N_EDGES * 8;
    __half* bufH = (__half*)w;         w += (size_t)N_NODES * F * 2;  // h (gather src)
    __half* bufB = (__half*)w;         w += (size_t)N_NODES * F * 2;  // agg out (fp16)
    ull* brec = (ull*)bufH;            // 8MB, dead before gemm1 writes bufH

    k_zero256<<<1, 256, 0, stream>>>(gcnt);
    k_bcount<<<N_EDGES / 4096, 256, 0, stream>>>(dstArr, gcnt);
    k_bscan<<<1, 256, 0, stream>>>(gcnt, boff, gfill);
    k_bpart<<<N_EDGES / 4096, 256, 0, stream>>>(srcArr, dstArr, ew, gfill, brec);
    k_build<<<NBUCK, 256, 0, stream>>>(brec, boff, dinv, row_ptr, edge8);
    k_coef<<<N_EDGES / 1024, 256, 0, stream>>>(edge8, dinv);

    // layer 1: h1 fp16 = x @ W1 (hi/lo emulated fp32)
    k_gemm_mfma<<<512, 256, 0, stream>>>(x, W1, bufH);
    k_aggregate<<<N_NODES / 8, 256, 0, stream>>>((const __half2*)bufH, row_ptr, edge8,
                                                 dinv, b1, (__half2*)bufB);
    // layer 2: h2 fp16 = agg1(fp16) @ W2
    k_gemm_mfma_h<<<512, 256, 0, stream>>>(bufB, W2, bufH);
    k_aggregate<<<N_NODES / 8, 256, 0, stream>>>((const __half2*)bufH, row_ptr, edge8,
                                                 dinv, b2, (__half2*)bufB);
    // FC: out fp32 = agg2(fp16) @ fcW + fcb
    k_fc_mfma_h<<<512, 256, 0, stream>>>(bufB, fcW, fcb, out);
}